// Round 1
// baseline (559.990 us; speedup 1.0000x reference)
//
#include <hip/hip_runtime.h>
#include <hip/hip_bf16.h>
#include <math.h>

// Problem constants (SemanticAwareTransitions_9826885173968)
#define V_  512
#define D_  256
#define H_  8
#define DH_ 32
#define FF_ 2048
#define L_  2
#define B_  4
#define S_  128
#define T_  (B_*S_)   // 512 tokens

typedef float f32x4 __attribute__((ext_vector_type(4)));

// ---------------------------------------------------------------------------
// Generic tiled fp32 GEMM: C[M,N] = A[M,K] @ W[K,N] (+bias)(+relu)(*scale)
// BM=128, BN=64, BK=16, 256 threads, 8x4 microtile per thread.
// Optional split-K via gridDim.z with atomicAdd into pre-initialized C.
// ---------------------------------------------------------------------------
#define BM  128
#define BN  64
#define BKK 16

__device__ __forceinline__ void gemm_body(const float* __restrict__ A,
                                          const float* __restrict__ W,
                                          const float* __restrict__ bias,
                                          float* __restrict__ C,
                                          int M, int N, int K,
                                          int kBegin, int kSteps,
                                          float scale, int relu, int atomic)
{
    __shared__ float As[BKK][BM + 4];   // stored transposed: As[k][m]
    __shared__ float Bs[BKK][BN + 4];
    const int tid  = threadIdx.x;
    const int m0   = blockIdx.y * BM;
    const int n0   = blockIdx.x * BN;
    const int tx   = tid & 15;          // 0..15 -> 4 cols each
    const int ty   = tid >> 4;          // 0..15 -> 8 rows each
    const int arow = tid >> 1;          // 0..127
    const int ak   = (tid & 1) * 8;     // 0 or 8

    float acc[8][4];
#pragma unroll
    for (int i = 0; i < 8; ++i)
#pragma unroll
        for (int j = 0; j < 4; ++j) acc[i][j] = 0.f;

    for (int kt = 0; kt < kSteps; ++kt) {
        const int k0 = kBegin + kt * BKK;
        f32x4 a0 = *(const f32x4*)&A[(size_t)(m0 + arow) * K + k0 + ak];
        f32x4 a1 = *(const f32x4*)&A[(size_t)(m0 + arow) * K + k0 + ak + 4];
        f32x4 b  = *(const f32x4*)&W[(size_t)(k0 + ty) * N + n0 + tx * 4];
        __syncthreads();   // previous iteration's compute done before overwrite
#pragma unroll
        for (int e = 0; e < 4; ++e) {
            As[ak + e][arow]     = a0[e];
            As[ak + 4 + e][arow] = a1[e];
        }
        *(f32x4*)&Bs[ty][tx * 4] = b;
        __syncthreads();
#pragma unroll
        for (int kk = 0; kk < BKK; ++kk) {
            f32x4 xa = *(const f32x4*)&As[kk][ty * 8];
            f32x4 xb = *(const f32x4*)&As[kk][ty * 8 + 4];
            f32x4 yb = *(const f32x4*)&Bs[kk][tx * 4];
#pragma unroll
            for (int i = 0; i < 4; ++i)
#pragma unroll
                for (int j = 0; j < 4; ++j) {
                    acc[i][j]     = fmaf(xa[i], yb[j], acc[i][j]);
                    acc[4 + i][j] = fmaf(xb[i], yb[j], acc[4 + i][j]);
                }
        }
    }

#pragma unroll
    for (int i = 0; i < 8; ++i) {
        const int m = m0 + ty * 8 + i;
#pragma unroll
        for (int j = 0; j < 4; ++j) {
            const int n = n0 + tx * 4 + j;
            float v = acc[i][j] * scale;
            if (atomic) {
                atomicAdd(&C[(size_t)m * N + n], v);
            } else {
                if (bias) v += bias[n];
                if (relu) v = fmaxf(v, 0.f);
                C[(size_t)m * N + n] = v;
            }
        }
    }
}

__global__ __launch_bounds__(256) void gemm_k(const float* __restrict__ A,
                                              const float* __restrict__ W,
                                              const float* __restrict__ bias,
                                              float* __restrict__ C,
                                              int M, int N, int K,
                                              float scale, int relu, int atomic)
{
    const int gz = gridDim.z;
    const int Kc = K / gz;
    gemm_body(A, W, bias, C, M, N, K, blockIdx.z * Kc, Kc / BKK, scale, relu, atomic);
}

// Q,K,V in one launch (z selects which projection) -> 48 blocks instead of 3x16.
__global__ __launch_bounds__(256) void gemm_qkv_k(const float* __restrict__ X,
        const float* __restrict__ Wq, const float* __restrict__ Wk, const float* __restrict__ Wv,
        const float* __restrict__ bq, const float* __restrict__ bk, const float* __restrict__ bv,
        float* __restrict__ Q, float* __restrict__ Kt, float* __restrict__ Vt)
{
    const float* W; const float* bb; float* C;
    if (blockIdx.z == 0)      { W = Wq; bb = bq; C = Q;  }
    else if (blockIdx.z == 1) { W = Wk; bb = bk; C = Kt; }
    else                      { W = Wv; bb = bv; C = Vt; }
    gemm_body(X, W, bb, C, T_, D_, D_, 0, D_ / BKK, 1.f, 0, 0);
}

// ---------------------------------------------------------------------------
// Reductions
// ---------------------------------------------------------------------------
__device__ __forceinline__ float waveReduceSum(float v) {
#pragma unroll
    for (int off = 32; off > 0; off >>= 1) v += __shfl_xor(v, off);
    return v;
}
__device__ __forceinline__ float waveReduceMax(float v) {
#pragma unroll
    for (int off = 32; off > 0; off >>= 1) v = fmaxf(v, __shfl_xor(v, off));
    return v;
}

// ---------------------------------------------------------------------------
// Small kernels
// ---------------------------------------------------------------------------
__global__ void embed_k(const int* __restrict__ xt, const float* __restrict__ emb,
                        float* __restrict__ X)
{
    int idx = blockIdx.x * 256 + threadIdx.x;        // < T_*D_
    int t = idx >> 8, d = idx & 255;
    X[idx] = emb[(size_t)xt[t] * D_ + d];
}

__global__ void transpose_emb_k(const float* __restrict__ emb, float* __restrict__ embT)
{
    int idx = blockIdx.x * 256 + threadIdx.x;        // < V_*D_
    int n = idx >> 8, k = idx & 255;
    embT[(size_t)k * V_ + n] = emb[idx];
}

__global__ void init_bias_k(float* __restrict__ C, const float* __restrict__ bias)
{
    int idx = blockIdx.x * 256 + threadIdx.x;        // < T_*D_
    C[idx] = bias[idx & 255];
}

// x = LayerNorm(x + tmp) * s + b   (row = one token, 256 threads = 1 elem each)
__global__ __launch_bounds__(256) void add_ln_k(const float* __restrict__ tmp,
                                                float* __restrict__ x,
                                                const float* __restrict__ s,
                                                const float* __restrict__ b)
{
    __shared__ float lds[4];
    const int row = blockIdx.x, tid = threadIdx.x;
    float a = tmp[(size_t)row * D_ + tid] + x[(size_t)row * D_ + tid];

    float ws_ = waveReduceSum(a);
    if ((tid & 63) == 0) lds[tid >> 6] = ws_;
    __syncthreads();
    float mean = (lds[0] + lds[1] + lds[2] + lds[3]) * (1.f / D_);
    __syncthreads();

    float d = a - mean;
    float vs = waveReduceSum(d * d);
    if ((tid & 63) == 0) lds[tid >> 6] = vs;
    __syncthreads();
    float var = (lds[0] + lds[1] + lds[2] + lds[3]) * (1.f / D_);

    x[(size_t)row * D_ + tid] = d * rsqrtf(var + 1e-5f) * s[tid] + b[tid];
}

// scores[b,h,i,j] = scale * dot(Q[b,i,h,:], K[b,j,h,:])   -- one block per (b,h)
__global__ __launch_bounds__(256) void attn_scores_k(const float* __restrict__ Q,
                                                     const float* __restrict__ Km,
                                                     float* __restrict__ P)
{
    __shared__ float Qs[S_][DH_ + 1];
    __shared__ float Ks[S_][DH_ + 1];
    const int bh = blockIdx.x, b = bh >> 3, h = bh & 7;
    const int tid = threadIdx.x;
#pragma unroll
    for (int r = 0; r < 16; ++r) {
        int idx = r * 256 + tid;
        int row = idx >> 5, col = idx & 31;
        Qs[row][col] = Q [(size_t)(b * S_ + row) * D_ + h * DH_ + col];
        Ks[row][col] = Km[(size_t)(b * S_ + row) * D_ + h * DH_ + col];
    }
    __syncthreads();
    const float sc = 0.17677669529663687f;   // 1/sqrt(32)
    for (int r = 0; r < 64; ++r) {
        int idx = r * 256 + tid;
        int i = idx >> 7, j = idx & 127;
        float s = 0.f;
#pragma unroll
        for (int d = 0; d < DH_; ++d) s = fmaf(Qs[i][d], Ks[j][d], s);
        P[(size_t)bh * S_ * S_ + (size_t)i * S_ + j] = s * sc;
    }
}

// softmax over rows of length 128 (one block = one row, 128 threads)
__global__ __launch_bounds__(128) void softmax128_k(float* __restrict__ P)
{
    __shared__ float lds[2];
    const int row = blockIdx.x, tid = threadIdx.x;
    float v = P[(size_t)row * S_ + tid];
    float m = waveReduceMax(v);
    if ((tid & 63) == 0) lds[tid >> 6] = m;
    __syncthreads();
    m = fmaxf(lds[0], lds[1]);
    __syncthreads();
    float e = expf(v - m);
    float s = waveReduceSum(e);
    if ((tid & 63) == 0) lds[tid >> 6] = s;
    __syncthreads();
    s = lds[0] + lds[1];
    P[(size_t)row * S_ + tid] = e / s;
}

// O[b,i,h,d] = sum_j P[b,h,i,j] * V[b,j,h,d]   -- one block per (b,h)
__global__ __launch_bounds__(256) void attn_pv_k(const float* __restrict__ P,
                                                 const float* __restrict__ Vm,
                                                 float* __restrict__ O)
{
    __shared__ float Vs[S_][DH_ + 1];
    const int bh = blockIdx.x, b = bh >> 3, h = bh & 7;
    const int tid = threadIdx.x;
#pragma unroll
    for (int r = 0; r < 16; ++r) {
        int idx = r * 256 + tid;
        int row = idx >> 5, col = idx & 31;
        Vs[row][col] = Vm[(size_t)(b * S_ + row) * D_ + h * DH_ + col];
    }
    __syncthreads();
    for (int r = 0; r < 16; ++r) {
        int idx = r * 256 + tid;
        int d = idx & 31, i = idx >> 5;
        const float* pr = &P[(size_t)bh * S_ * S_ + (size_t)i * S_];
        float s = 0.f;
#pragma unroll 8
        for (int j = 0; j < S_; ++j) s = fmaf(pr[j], Vs[j][d], s);
        O[(size_t)(b * S_ + i) * D_ + h * DH_ + d] = s;
    }
}

// tp[t,:] = softmax(logits[t,:] / temperature), in place. 512 cols, 256 thr.
__global__ __launch_bounds__(256) void softmax_tp_k(float* __restrict__ logits,
                                                    const float* __restrict__ temp)
{
    __shared__ float lds[4];
    const int t = blockIdx.x, tid = threadIdx.x;
    const float rT = 1.f / temp[0];
    float l0 = logits[(size_t)t * V_ + tid] * rT;
    float l1 = logits[(size_t)t * V_ + 256 + tid] * rT;
    float m = waveReduceMax(fmaxf(l0, l1));
    if ((tid & 63) == 0) lds[tid >> 6] = m;
    __syncthreads();
    m = fmaxf(fmaxf(lds[0], lds[1]), fmaxf(lds[2], lds[3]));
    __syncthreads();
    float e0 = expf(l0 - m), e1 = expf(l1 - m);
    float s = waveReduceSum(e0 + e1);
    if ((tid & 63) == 0) lds[tid >> 6] = s;
    __syncthreads();
    s = lds[0] + lds[1] + lds[2] + lds[3];
    float inv = 1.f / s;
    logits[(size_t)t * V_ + tid]       = e0 * inv;
    logits[(size_t)t * V_ + 256 + tid] = e1 * inv;
}

// out[t, i, :] = tp[t, :] for all i.  2048 blocks: (t, quarter-of-i-range).
// Wave stores 1KB contiguous per iteration; nontemporal (streaming 512MB).
__global__ __launch_bounds__(256) void broadcast_k(const float* __restrict__ tp,
                                                   float* __restrict__ out)
{
    const int blk = blockIdx.x;
    const int t = blk >> 2, quarter = blk & 3;
    const int tid = threadIdx.x;
    const int c = tid & 127, ihalf = tid >> 7;
    f32x4 v = *(const f32x4*)&tp[(size_t)t * V_ + c * 4];
    f32x4* dst = (f32x4*)out + (size_t)t * V_ * (V_ / 4);
#pragma unroll 4
    for (int r = 0; r < 64; ++r) {
        int i = quarter * 128 + ihalf + r * 2;
        __builtin_nontemporal_store(v, &dst[(size_t)i * (V_ / 4) + c]);
    }
}

// ---------------------------------------------------------------------------
// Host launch.  Workspace layout (floats); requires ws_size >= 10.5 MB.
// ---------------------------------------------------------------------------
extern "C" void kernel_launch(void* const* d_in, const int* in_sizes, int n_in,
                              void* d_out, int out_size, void* d_ws, size_t ws_size,
                              hipStream_t stream)
{
    const int*   x_t  = (const int*)  d_in[0];
    const float* emb  = (const float*)d_in[1];
    const float* temp = (const float*)d_in[2];
    const float* Wq   = (const float*)d_in[3];
    const float* Wk   = (const float*)d_in[4];
    const float* Wv   = (const float*)d_in[5];
    const float* Wo   = (const float*)d_in[6];
    const float* bq   = (const float*)d_in[7];
    const float* bk   = (const float*)d_in[8];
    const float* bv   = (const float*)d_in[9];
    const float* bo   = (const float*)d_in[10];
    const float* W1   = (const float*)d_in[11];
    const float* b1   = (const float*)d_in[12];
    const float* W2   = (const float*)d_in[13];
    const float* b2   = (const float*)d_in[14];
    const float* ln1s = (const float*)d_in[15];
    const float* ln1b = (const float*)d_in[16];
    const float* ln2s = (const float*)d_in[17];
    const float* ln2b = (const float*)d_in[18];

    float* out = (float*)d_out;
    float* ws  = (float*)d_ws;

    float* X   = ws;              // 131072
    float* Qb  = ws + 131072;     // 131072
    float* Kb  = ws + 262144;     // 131072
    float* Vb  = ws + 393216;     // 131072
    float* Ob  = ws + 524288;     // 131072
    float* Tmp = ws + 655360;     // 131072
    float* Ff  = ws + 786432;     // 1048576
    float* P   = ws + 1835008;    // 524288  (B*H*S*S)
    float* Lg  = ws + 2359296;    // 262144  (T*V) -> becomes tp
    float* EmT = ws + 2621440;    // 131072  total 2752512 floats = 10.5 MB

    embed_k<<<512, 256, 0, stream>>>(x_t, emb, X);
    transpose_emb_k<<<512, 256, 0, stream>>>(emb, EmT);

    for (int l = 0; l < L_; ++l) {
        const float* wq = Wq + (size_t)l * D_ * D_;
        const float* wk = Wk + (size_t)l * D_ * D_;
        const float* wv = Wv + (size_t)l * D_ * D_;
        const float* wo = Wo + (size_t)l * D_ * D_;
        const float* w1 = W1 + (size_t)l * D_ * FF_;
        const float* w2 = W2 + (size_t)l * FF_ * D_;

        gemm_qkv_k<<<dim3(D_ / BN, T_ / BM, 3), 256, 0, stream>>>(
            X, wq, wk, wv, bq + l * D_, bk + l * D_, bv + l * D_, Qb, Kb, Vb);

        attn_scores_k<<<B_ * H_, 256, 0, stream>>>(Qb, Kb, P);
        softmax128_k<<<B_ * H_ * S_, 128, 0, stream>>>(P);
        attn_pv_k<<<B_ * H_, 256, 0, stream>>>(P, Vb, Ob);

        gemm_k<<<dim3(D_ / BN, T_ / BM, 1), 256, 0, stream>>>(
            Ob, wo, bo + l * D_, Tmp, T_, D_, D_, 1.f, 0, 0);
        add_ln_k<<<T_, 256, 0, stream>>>(Tmp, X, ln1s + l * D_, ln1b + l * D_);

        gemm_k<<<dim3(FF_ / BN, T_ / BM, 1), 256, 0, stream>>>(
            X, w1, b1 + l * FF_, Ff, T_, FF_, D_, 1.f, 1, 0);

        init_bias_k<<<512, 256, 0, stream>>>(Tmp, b2 + l * D_);
        gemm_k<<<dim3(D_ / BN, T_ / BM, 8), 256, 0, stream>>>(
            Ff, w2, nullptr, Tmp, T_, D_, FF_, 1.f, 0, 1);
        add_ln_k<<<T_, 256, 0, stream>>>(Tmp, X, ln2s + l * D_, ln2b + l * D_);
    }

    gemm_k<<<dim3(V_ / BN, T_ / BM, 1), 256, 0, stream>>>(
        X, EmT, nullptr, Lg, T_, V_, D_, 1.f, 0, 0);
    softmax_tp_k<<<T_, 256, 0, stream>>>(Lg, temp);
    broadcast_k<<<T_ * 4, 256, 0, stream>>>(Lg, out);
}

// Round 2
// 202.649 us; speedup vs baseline: 2.7634x; 2.7634x over previous
//
#include <hip/hip_runtime.h>
#include <math.h>

// Problem constants (SemanticAwareTransitions_9826885173968)
#define V_  512
#define D_  256
#define H_  8
#define DH_ 32
#define FF_ 2048
#define L_  2
#define B_  4
#define S_  128
#define T_  (B_*S_)   // 512 tokens

typedef float f32x4 __attribute__((ext_vector_type(4)));
typedef short s16x8 __attribute__((ext_vector_type(8)));
typedef unsigned short u16x4 __attribute__((ext_vector_type(4)));
typedef unsigned short ushort_t;

// fp32 -> bf16 bits, round-to-nearest-even
__device__ __forceinline__ ushort_t f2b(float f) {
    unsigned int u = __builtin_bit_cast(unsigned int, f);
    u += 0x7FFFu + ((u >> 16) & 1u);
    return (ushort_t)(u >> 16);
}
__device__ __forceinline__ float b2f(ushort_t h) {
    unsigned int u = ((unsigned int)h) << 16;
    return __builtin_bit_cast(float, u);
}

__device__ __forceinline__ float waveReduceSum(float v) {
#pragma unroll
    for (int off = 32; off > 0; off >>= 1) v += __shfl_xor(v, off);
    return v;
}
__device__ __forceinline__ float waveReduceMax(float v) {
#pragma unroll
    for (int off = 32; off > 0; off >>= 1) v = fmaxf(v, __shfl_xor(v, off));
    return v;
}

// ---------------------------------------------------------------------------
// bf16 MFMA GEMM: C[M,N] = A[M,K] @ BT[N,K]^T  (both inputs bf16 row-major,
// B given TRANSPOSED so both fragment loads are contiguous 16B).
// Tile 64x64, BK=32, 256 thr = 4 waves; wave w owns cols w*16..w*16+15.
// mfma_f32_16x16x32_bf16:  A row = lane&15, k = (lane>>4)*8+j  (B symmetric);
// D: col = lane&15, row = (lane>>4)*4 + reg   [verified layout, learn_hip m89]
// ---------------------------------------------------------------------------
template<int RELU, int OUTB, int BIAS>
__device__ __forceinline__ void mgemm_body(
    const ushort_t* __restrict__ A, const ushort_t* __restrict__ BT,
    const float* __restrict__ bias, float* __restrict__ Cf,
    ushort_t* __restrict__ Cb, int M, int N, int K, int kBegin, int kSteps)
{
    __shared__ ushort_t Al[64][40];   // +8 bf16 pad: rows 16B-aligned, banks spread
    __shared__ ushort_t Bl[64][40];
    const int tid  = threadIdx.x;
    const int m0   = blockIdx.y * 64, n0 = blockIdx.x * 64;
    const int lane = tid & 63, w = tid >> 6;
    const int srow = tid >> 2, sseg = (tid & 3) * 8;
    const int l15  = lane & 15,  kg = (lane >> 4) * 8;

    f32x4 acc0 = {0.f,0.f,0.f,0.f}, acc1 = acc0, acc2 = acc0, acc3 = acc0;

    for (int kt = 0; kt < kSteps; ++kt) {
        const int k0 = kBegin + kt * 32;
        s16x8 av = *(const s16x8*)&A [(size_t)(m0 + srow) * K + k0 + sseg];
        s16x8 bv = *(const s16x8*)&BT[(size_t)(n0 + srow) * K + k0 + sseg];
        __syncthreads();
        *(s16x8*)&Al[srow][sseg] = av;
        *(s16x8*)&Bl[srow][sseg] = bv;
        __syncthreads();
        s16x8 bfr = *(const s16x8*)&Bl[w * 16 + l15][kg];
        s16x8 a0  = *(const s16x8*)&Al[     l15][kg];
        s16x8 a1  = *(const s16x8*)&Al[16 + l15][kg];
        s16x8 a2  = *(const s16x8*)&Al[32 + l15][kg];
        s16x8 a3  = *(const s16x8*)&Al[48 + l15][kg];
        acc0 = __builtin_amdgcn_mfma_f32_16x16x32_bf16(a0, bfr, acc0, 0, 0, 0);
        acc1 = __builtin_amdgcn_mfma_f32_16x16x32_bf16(a1, bfr, acc1, 0, 0, 0);
        acc2 = __builtin_amdgcn_mfma_f32_16x16x32_bf16(a2, bfr, acc2, 0, 0, 0);
        acc3 = __builtin_amdgcn_mfma_f32_16x16x32_bf16(a3, bfr, acc3, 0, 0, 0);
    }

    const int col = n0 + w * 16 + l15;
    const float bb = BIAS ? bias[col] : 0.f;
    f32x4 accs[4] = {acc0, acc1, acc2, acc3};
#pragma unroll
    for (int r = 0; r < 4; ++r) {
#pragma unroll
        for (int e = 0; e < 4; ++e) {
            const int row = m0 + r * 16 + (lane >> 4) * 4 + e;
            float v = accs[r][e] + bb;
            if (RELU) v = fmaxf(v, 0.f);
            if (OUTB) Cb[(size_t)row * N + col] = f2b(v);
            else      Cf[(size_t)row * N + col] = v;
        }
    }
}

// Generic: gridDim.z>1 => split-K, partial z writes Cf + z*M*N (fp32).
template<int RELU, int OUTB, int BIAS>
__global__ __launch_bounds__(256) void mgemm_k(const ushort_t* A, const ushort_t* BT,
    const float* bias, float* Cf, ushort_t* Cb, int M, int N, int K, int kChunk)
{
    const int z = blockIdx.z;
    mgemm_body<RELU, OUTB, BIAS>(A, BT, bias, Cf + (size_t)z * M * N, Cb,
                                 M, N, K, z * kChunk, kChunk / 32);
}

// QKV fused: blockIdx.z selects projection.
__global__ __launch_bounds__(256) void qkv_k(const ushort_t* Xb, const ushort_t* WT,
    const float* bq, const float* bk, const float* bv,
    ushort_t* Qb, ushort_t* Kb, ushort_t* Vb)
{
    const int z = blockIdx.z;
    const ushort_t* bt = WT + (size_t)z * (D_ * D_);
    const float* bias; ushort_t* out;
    if (z == 0)      { bias = bq; out = Qb; }
    else if (z == 1) { bias = bk; out = Kb; }
    else             { bias = bv; out = Vb; }
    mgemm_body<0, 1, 1>(Xb, bt, bias, (float*)out, out, T_, D_, D_, 0, D_ / 32);
}

// ---------------------------------------------------------------------------
// One-time prep: embedding gather (+bf16 copies) and weight transpose->bf16.
// ---------------------------------------------------------------------------
__global__ void embed_k(const int* __restrict__ xt, const float* __restrict__ emb,
                        float* __restrict__ X, ushort_t* __restrict__ Xb,
                        ushort_t* __restrict__ embB)
{
    const int idx = blockIdx.x * 256 + threadIdx.x;   // < T_*D_ == V_*D_
    const int t = idx >> 8, d = idx & 255;
    const float v = emb[(size_t)xt[t] * D_ + d];
    X[idx]  = v;
    Xb[idx] = f2b(v);
    embB[idx] = f2b(emb[idx]);
}

// Transpose fp32 [R][C] -> bf16 [C][R], 32x32 LDS tiles. 2560 tiles total:
// per layer: Wq,Wk,Wv,Wo (64 tiles each), W1 (512), W2 (512).
__global__ __launch_bounds__(256) void transw_k(
    const float* __restrict__ Wq, const float* __restrict__ Wk,
    const float* __restrict__ Wv, const float* __restrict__ Wo,
    const float* __restrict__ W1, const float* __restrict__ W2,
    ushort_t* __restrict__ WT, ushort_t* __restrict__ W1T, ushort_t* __restrict__ W2T)
{
    const int id = blockIdx.x;
    const int l  = id >= 1280 ? 1 : 0;
    int t = id - l * 1280;
    const float* src; ushort_t* dst; int R, C, rt, ct;
    if (t < 256) {
        const int kind = t >> 6, tl = t & 63;
        const float* s0 = (kind == 0) ? Wq : (kind == 1) ? Wk : (kind == 2) ? Wv : Wo;
        src = s0 + (size_t)l * (D_ * D_);
        dst = WT + (size_t)l * (4 * D_ * D_) + (size_t)kind * (D_ * D_);
        R = D_; C = D_; rt = tl >> 3; ct = tl & 7;
    } else if (t < 768) {
        const int tl = t - 256;
        src = W1 + (size_t)l * (D_ * FF_); dst = W1T + (size_t)l * (D_ * FF_);
        R = D_; C = FF_; rt = tl >> 6; ct = tl & 63;
    } else {
        const int tl = t - 768;
        src = W2 + (size_t)l * (FF_ * D_); dst = W2T + (size_t)l * (FF_ * D_);
        R = FF_; C = D_; rt = tl >> 3; ct = tl & 7;
    }
    __shared__ float Tl[32][33];
    const int tid = threadIdx.x;
    const int r = tid >> 3, c4 = (tid & 7) * 4;
    f32x4 v = *(const f32x4*)&src[(size_t)(rt * 32 + r) * C + ct * 32 + c4];
    Tl[r][c4] = v[0]; Tl[r][c4 + 1] = v[1]; Tl[r][c4 + 2] = v[2]; Tl[r][c4 + 3] = v[3];
    __syncthreads();
    u16x4 ov;
    ov[0] = f2b(Tl[c4 + 0][r]); ov[1] = f2b(Tl[c4 + 1][r]);
    ov[2] = f2b(Tl[c4 + 2][r]); ov[3] = f2b(Tl[c4 + 3][r]);
    *(u16x4*)&dst[(size_t)(ct * 32 + r) * R + rt * 32 + c4] = ov;
}

// ---------------------------------------------------------------------------
// x = LN(x + sum_p parts[p] + bias) * s + b ; writes fp32 X and bf16 Xb.
// ---------------------------------------------------------------------------
__global__ __launch_bounds__(256) void add_ln_k(const float* __restrict__ parts, int nparts,
    const float* __restrict__ bias, float* __restrict__ X, ushort_t* __restrict__ Xb,
    const float* __restrict__ s, const float* __restrict__ b)
{
    __shared__ float red[4];
    const int row = blockIdx.x, tid = threadIdx.x;
    float a = X[(size_t)row * D_ + tid] + bias[tid];
    for (int p = 0; p < nparts; ++p)
        a += parts[(size_t)p * T_ * D_ + (size_t)row * D_ + tid];

    float ws_ = waveReduceSum(a);
    if ((tid & 63) == 0) red[tid >> 6] = ws_;
    __syncthreads();
    const float mean = (red[0] + red[1] + red[2] + red[3]) * (1.f / D_);
    __syncthreads();
    const float d = a - mean;
    float vs = waveReduceSum(d * d);
    if ((tid & 63) == 0) red[tid >> 6] = vs;
    __syncthreads();
    const float var = (red[0] + red[1] + red[2] + red[3]) * (1.f / D_);
    const float y = d * rsqrtf(var + 1e-5f) * s[tid] + b[tid];
    X[(size_t)row * D_ + tid]  = y;
    Xb[(size_t)row * D_ + tid] = f2b(y);
}

// ---------------------------------------------------------------------------
// Fused attention: one block per (b,h,q-quarter of 32 rows). fp32 math,
// bf16 in (Q,K,V) / bf16 out (Ob). scores -> softmax -> PV in LDS/regs.
// ---------------------------------------------------------------------------
__global__ __launch_bounds__(256) void attn_k(const ushort_t* __restrict__ Qb,
    const ushort_t* __restrict__ Kb, const ushort_t* __restrict__ Vb,
    ushort_t* __restrict__ Ob)
{
    __shared__ float Qs[32][36], Ks[128][36], Vs[128][36], Ps[32][132];
    const int bh = blockIdx.x, b = bh >> 3, h = bh & 7;
    const int i0 = blockIdx.y * 32;
    const int tid = threadIdx.x;

#pragma unroll
    for (int it = 0; it < 16; ++it) {
        const int idx = it * 256 + tid, r = idx >> 5, c = idx & 31;
        Ks[r][c] = b2f(Kb[(size_t)(b * S_ + r) * D_ + h * DH_ + c]);
        Vs[r][c] = b2f(Vb[(size_t)(b * S_ + r) * D_ + h * DH_ + c]);
    }
#pragma unroll
    for (int it = 0; it < 4; ++it) {
        const int idx = it * 256 + tid, r = idx >> 5, c = idx & 31;
        Qs[r][c] = b2f(Qb[(size_t)(b * S_ + i0 + r) * D_ + h * DH_ + c]);
    }
    __syncthreads();

    const int i = tid >> 3, jg = tid & 7;     // 32 rows x 8-thread octets
    const float sc = 0.17677669529663687f;    // 1/sqrt(32)
    float sv[16];
    float mx = -1e30f;
#pragma unroll
    for (int jj = 0; jj < 16; ++jj) {
        const int j = jg + jj * 8;            // bank-friendly interleave
        f32x4 a4 = {0.f,0.f,0.f,0.f};
#pragma unroll
        for (int kk = 0; kk < 8; ++kk) {
            f32x4 q = *(const f32x4*)&Qs[i][kk * 4];
            f32x4 k = *(const f32x4*)&Ks[j][kk * 4];
            a4 += q * k;
        }
        const float sdot = (a4[0] + a4[1] + a4[2] + a4[3]) * sc;
        sv[jj] = sdot;
        mx = fmaxf(mx, sdot);
    }
    mx = fmaxf(mx, __shfl_xor(mx, 1));
    mx = fmaxf(mx, __shfl_xor(mx, 2));
    mx = fmaxf(mx, __shfl_xor(mx, 4));
    float sum = 0.f;
#pragma unroll
    for (int jj = 0; jj < 16; ++jj) {
        const float e = __expf(sv[jj] - mx);
        Ps[i][jg + jj * 8] = e;
        sum += e;
    }
    sum += __shfl_xor(sum, 1);
    sum += __shfl_xor(sum, 2);
    sum += __shfl_xor(sum, 4);
    const float inv = 1.f / sum;
    __syncthreads();

    const int dg = tid & 7;                   // 4 head-dims per thread
    f32x4 o = {0.f,0.f,0.f,0.f};
#pragma unroll 4
    for (int j = 0; j < 128; ++j) {
        const float p = Ps[i][j];
        f32x4 vv = *(const f32x4*)&Vs[j][dg * 4];
        o += vv * p;
    }
    u16x4 ov;
    ov[0] = f2b(o[0] * inv); ov[1] = f2b(o[1] * inv);
    ov[2] = f2b(o[2] * inv); ov[3] = f2b(o[3] * inv);
    *(u16x4*)&Ob[(size_t)(b * S_ + i0 + i) * D_ + h * DH_ + dg * 4] = ov;
}

// ---------------------------------------------------------------------------
// Fused final softmax + broadcast: block = (token t, quarter of row-range).
// Each block re-computes softmax(t) (cheap, 4x redundant) then streams 128
// rows of 2KB with nontemporal float4 stores.
// ---------------------------------------------------------------------------
__global__ __launch_bounds__(256) void bcast_k(const float* __restrict__ Lg,
    const float* __restrict__ temp, float* __restrict__ out)
{
    __shared__ float row[V_];
    __shared__ float red[4];
    const int blk = blockIdx.x, t = blk >> 2, quarter = blk & 3;
    const int tid = threadIdx.x;
    const float rT = 1.f / temp[0];
    const float l0 = Lg[(size_t)t * V_ + tid] * rT;
    const float l1 = Lg[(size_t)t * V_ + 256 + tid] * rT;
    float m = waveReduceMax(fmaxf(l0, l1));
    if ((tid & 63) == 0) red[tid >> 6] = m;
    __syncthreads();
    m = fmaxf(fmaxf(red[0], red[1]), fmaxf(red[2], red[3]));
    __syncthreads();
    const float e0 = __expf(l0 - m), e1 = __expf(l1 - m);
    float sblk = waveReduceSum(e0 + e1);
    if ((tid & 63) == 0) red[tid >> 6] = sblk;
    __syncthreads();
    const float inv = 1.f / (red[0] + red[1] + red[2] + red[3]);
    row[tid] = e0 * inv;
    row[tid + 256] = e1 * inv;
    __syncthreads();

    const int c = tid & 127, ihalf = tid >> 7;
    f32x4 v = *(const f32x4*)&row[c * 4];
    f32x4* dst = (f32x4*)out + (size_t)t * V_ * (V_ / 4);
#pragma unroll 4
    for (int r = 0; r < 64; ++r) {
        const int i = quarter * 128 + ihalf + r * 2;
        __builtin_nontemporal_store(v, &dst[(size_t)i * (V_ / 4) + c]);
    }
}

// ---------------------------------------------------------------------------
// Host launch. ws layout (bytes), total 10.0 MB:
//   0        X     fp32 512KB
//   524288   Part  fp32 2x512KB (split-K partials / Wo out; aliased as Lg 1MB)
//   1572864  Qb    bf16 256KB
//   1835008  Kb    bf16 256KB
//   2097152  Vb    bf16 256KB
//   2359296  Ob    bf16 256KB
//   2621440  Xb    bf16 256KB
//   2883584  Ffb   bf16 2MB
//   4980736  embB  bf16 256KB
//   5242880  WT    bf16 1MB   (L x {Wq,Wk,Wv,Wo} transposed)
//   6291456  W1T   bf16 2MB
//   8388608  W2T   bf16 2MB   -> end 10485760
// ---------------------------------------------------------------------------
extern "C" void kernel_launch(void* const* d_in, const int* in_sizes, int n_in,
                              void* d_out, int out_size, void* d_ws, size_t ws_size,
                              hipStream_t stream)
{
    const int*   x_t  = (const int*)  d_in[0];
    const float* emb  = (const float*)d_in[1];
    const float* temp = (const float*)d_in[2];
    const float* Wq   = (const float*)d_in[3];
    const float* Wk   = (const float*)d_in[4];
    const float* Wv   = (const float*)d_in[5];
    const float* Wo   = (const float*)d_in[6];
    const float* bq   = (const float*)d_in[7];
    const float* bk   = (const float*)d_in[8];
    const float* bv   = (const float*)d_in[9];
    const float* bo   = (const float*)d_in[10];
    const float* W1   = (const float*)d_in[11];
    const float* b1   = (const float*)d_in[12];
    const float* W2   = (const float*)d_in[13];
    const float* b2   = (const float*)d_in[14];
    const float* ln1s = (const float*)d_in[15];
    const float* ln1b = (const float*)d_in[16];
    const float* ln2s = (const float*)d_in[17];
    const float* ln2b = (const float*)d_in[18];

    float* out = (float*)d_out;
    char*  wsb = (char*)d_ws;

    float*    X    = (float*)   (wsb + 0);
    float*    Part = (float*)   (wsb + 524288);
    float*    Lg   = Part;                         // alias (disjoint lifetime)
    ushort_t* Qb   = (ushort_t*)(wsb + 1572864);
    ushort_t* Kb   = (ushort_t*)(wsb + 1835008);
    ushort_t* Vb   = (ushort_t*)(wsb + 2097152);
    ushort_t* Ob   = (ushort_t*)(wsb + 2359296);
    ushort_t* Xb   = (ushort_t*)(wsb + 2621440);
    ushort_t* Ffb  = (ushort_t*)(wsb + 2883584);
    ushort_t* embB = (ushort_t*)(wsb + 4980736);
    ushort_t* WT   = (ushort_t*)(wsb + 5242880);
    ushort_t* W1T  = (ushort_t*)(wsb + 6291456);
    ushort_t* W2T  = (ushort_t*)(wsb + 8388608);

    embed_k <<<512, 256, 0, stream>>>(x_t, emb, X, Xb, embB);
    transw_k<<<2560, 256, 0, stream>>>(Wq, Wk, Wv, Wo, W1, W2, WT, W1T, W2T);

    for (int l = 0; l < L_; ++l) {
        const ushort_t* WTl  = WT  + (size_t)l * (4 * D_ * D_);
        const ushort_t* W1Tl = W1T + (size_t)l * (D_ * FF_);
        const ushort_t* W2Tl = W2T + (size_t)l * (FF_ * D_);

        qkv_k<<<dim3(4, 8, 3), 256, 0, stream>>>(
            Xb, WTl, bq + l * D_, bk + l * D_, bv + l * D_, Qb, Kb, Vb);

        attn_k<<<dim3(32, 4), 256, 0, stream>>>(Qb, Kb, Vb, Ob);

        // o @ Wo -> Part[0] (fp32); bias bo folded into add_ln
        mgemm_k<0, 0, 0><<<dim3(4, 8, 1), 256, 0, stream>>>(
            Ob, WTl + 3 * D_ * D_, nullptr, Part, (ushort_t*)Part, T_, D_, D_, D_);
        add_ln_k<<<T_, 256, 0, stream>>>(Part, 1, bo + l * D_, X, Xb,
                                         ln1s + l * D_, ln1b + l * D_);

        // relu(x @ W1 + b1) -> Ffb (bf16)
        mgemm_k<1, 1, 1><<<dim3(32, 8, 1), 256, 0, stream>>>(
            Xb, W1Tl, b1 + l * FF_, Part, Ffb, T_, FF_, D_, D_);

        // Ffb @ W2 split-K z=2 -> Part[0..1]; b2 folded into add_ln
        mgemm_k<0, 0, 0><<<dim3(4, 8, 2), 256, 0, stream>>>(
            Ffb, W2Tl, nullptr, Part, (ushort_t*)Part, T_, D_, FF_, FF_ / 2);
        add_ln_k<<<T_, 256, 0, stream>>>(Part, 2, b2 + l * D_, X, Xb,
                                         ln2s + l * D_, ln2b + l * D_);
    }

    // logits = Xb @ embB^T -> Lg (fp32)
    mgemm_k<0, 0, 0><<<dim3(8, 8, 1), 256, 0, stream>>>(
        Xb, embB, nullptr, Lg, (ushort_t*)Lg, T_, V_, D_, D_);

    bcast_k<<<T_ * 4, 256, 0, stream>>>(Lg, temp, out);
}